// Round 2
// baseline (671.841 us; speedup 1.0000x reference)
//
#include <hip/hip_runtime.h>

typedef __attribute__((ext_vector_type(8))) short short8;
typedef __attribute__((ext_vector_type(4))) float f32x4;
typedef unsigned short ushort_t;
typedef unsigned int uint_t;

#define MFMA16(a, b, c) __builtin_amdgcn_mfma_f32_16x16x32_bf16((a), (b), (c), 0, 0, 0)

constexpr int V = 10000;
constexpr int E = 640000;
constexpr int XS_STRIDE = 264;  // 256 + 8 pad (bf16): 16B-aligned rows
constexpr int YS_STRIDE = 136;  // 128 + 8 pad

__device__ __forceinline__ ushort_t f2b(float f) {
    uint_t u = __float_as_uint(f);
    u += 0x7FFFu + ((u >> 16) & 1u);
    return (ushort_t)(u >> 16);
}

__device__ __forceinline__ float silu(float x) {
    return x / (1.0f + __expf(-x));
}

// One kernel: bf16-convert h + 4 weight matrices, zero agg. Cuts 6 launches to 1.
constexpr int H4 = V * 128 / 4;      // 320000 float4 units
constexpr int W14 = 256 * 128 / 4;   // 8192
constexpr int W24 = 128 * 128 / 4;   // 4096
constexpr int AGG4 = V * 128 / 4;    // 320000
constexpr int PREP_TOTAL = H4 + 2 * W14 + 2 * W24 + AGG4;

__device__ __forceinline__ void cvt4(const float* __restrict__ s, ushort_t* __restrict__ d, int i) {
    float4 v = ((const float4*)s)[i];
    ushort4 o;
    o.x = f2b(v.x); o.y = f2b(v.y); o.z = f2b(v.z); o.w = f2b(v.w);
    ((ushort4*)d)[i] = o;
}

__global__ void prep_kernel(const float* __restrict__ h,
                            const float* __restrict__ ew1, const float* __restrict__ ew2,
                            const float* __restrict__ nw1, const float* __restrict__ nw2,
                            ushort_t* __restrict__ hb, ushort_t* __restrict__ w1b,
                            ushort_t* __restrict__ w2b, ushort_t* __restrict__ nw1b,
                            ushort_t* __restrict__ nw2b, float* __restrict__ agg) {
    int i = blockIdx.x * blockDim.x + threadIdx.x;
    if (i < H4) { cvt4(h, hb, i); return; }
    i -= H4;
    if (i < W14) { cvt4(ew1, w1b, i); return; }
    i -= W14;
    if (i < W24) { cvt4(ew2, w2b, i); return; }
    i -= W24;
    if (i < W14) { cvt4(nw1, nw1b, i); return; }
    i -= W14;
    if (i < W24) { cvt4(nw2, nw2b, i); return; }
    i -= W24;
    if (i < AGG4) ((float4*)agg)[i] = float4{0.f, 0.f, 0.f, 0.f};
}

// ---------------------------------------------------------------------------
// Edge kernel. Per 64-edge tile:
//   x = concat(h[row], h[col]) [64,256] bf16 (LDS xs)
//   y = silu(x@W1+b1)          [64,128] bf16 (LDS, overlaid on xs)
//   m = silu(y@W2+b2)          [64,128] fp32 -> mij store + atomicAdd agg[row]
// ys overlaid on xs (extra barriers) => LDS 34 KB => 4 blocks/CU.
// ---------------------------------------------------------------------------
__global__ __launch_bounds__(256, 4) void edge_kernel(
    const ushort_t* __restrict__ hb, const int* __restrict__ eidx,
    const ushort_t* __restrict__ w1, const float* __restrict__ eb1,
    const ushort_t* __restrict__ w2, const float* __restrict__ eb2,
    float* __restrict__ mij, float* __restrict__ agg) {
    __shared__ __align__(16) ushort_t xs[64 * XS_STRIDE];  // 33792 B; ys overlaid (needs 8704)
    __shared__ int ridx[64];
    ushort_t* ys = xs;

    const int tid = threadIdx.x;
    const int wave = tid >> 6;
    const int lane = tid & 63;
    const int quad = lane >> 4;
    const int ln = lane & 15;
    const int ncol0 = wave * 32;

    // B fragments register-resident across all tiles (lane holds B[k=quad*8+j][n=ln])
    short8 b1f[8][2];
    short8 b2f[4][2];
#pragma unroll
    for (int kk = 0; kk < 8; kk++)
#pragma unroll
        for (int t = 0; t < 2; t++) {
            short8 f;
#pragma unroll
            for (int j = 0; j < 8; j++)
                f[j] = ((const short*)w1)[(kk * 32 + quad * 8 + j) * 128 + ncol0 + t * 16 + ln];
            b1f[kk][t] = f;
        }
#pragma unroll
    for (int kk = 0; kk < 4; kk++)
#pragma unroll
        for (int t = 0; t < 2; t++) {
            short8 f;
#pragma unroll
            for (int j = 0; j < 8; j++)
                f[j] = ((const short*)w2)[(kk * 32 + quad * 8 + j) * 128 + ncol0 + t * 16 + ln];
            b2f[kk][t] = f;
        }
    const float bv1[2] = {eb1[ncol0 + ln], eb1[ncol0 + 16 + ln]};
    const float bv2[2] = {eb2[ncol0 + ln], eb2[ncol0 + 16 + ln]};

    for (int tile = blockIdx.x; tile < E / 64; tile += gridDim.x) {
        const int e0 = tile * 64;
        // ---- stage x tile: 4 threads/edge, 128 B each ----
        {
            const int e = tid >> 2, seg = tid & 3;
            const int r = eidx[e0 + e];
            const int c = eidx[E + e0 + e];
            if (seg == 0) ridx[e] = r;
            const int node = (seg < 2) ? r : c;
            const uint4* src = (const uint4*)(hb + node * 128 + (seg & 1) * 64);
            uint4* dst = (uint4*)(xs + e * XS_STRIDE + seg * 64);
#pragma unroll
            for (int u = 0; u < 8; u++) dst[u] = src[u];
        }
        __syncthreads();  // B1: xs staged

        // ---- layer 1 ----
        f32x4 acc[4][2];
#pragma unroll
        for (int mt = 0; mt < 4; mt++)
#pragma unroll
            for (int t = 0; t < 2; t++) acc[mt][t] = f32x4{bv1[t], bv1[t], bv1[t], bv1[t]};
#pragma unroll
        for (int kk = 0; kk < 8; kk++) {
#pragma unroll
            for (int mt = 0; mt < 4; mt++) {
                short8 a = *(const short8*)(xs + (mt * 16 + ln) * XS_STRIDE + kk * 32 + quad * 8);
                acc[mt][0] = MFMA16(a, b1f[kk][0], acc[mt][0]);
                acc[mt][1] = MFMA16(a, b1f[kk][1], acc[mt][1]);
            }
        }
        __syncthreads();  // B2: all xs reads complete; safe to overlay ys

        // silu -> bf16 -> ys (C/D layout: row = mt*16 + quad*4 + r, col = ncol0+t*16+ln)
#pragma unroll
        for (int mt = 0; mt < 4; mt++)
#pragma unroll
            for (int t = 0; t < 2; t++) {
#pragma unroll
                for (int r = 0; r < 4; r++) {
                    float s = silu(acc[mt][t][r]);
                    ys[(mt * 16 + quad * 4 + r) * YS_STRIDE + ncol0 + t * 16 + ln] = f2b(s);
                }
            }
        __syncthreads();  // B3: ys staged

        // ---- layer 2 ----
        f32x4 acc2[4][2];
#pragma unroll
        for (int mt = 0; mt < 4; mt++)
#pragma unroll
            for (int t = 0; t < 2; t++) acc2[mt][t] = f32x4{bv2[t], bv2[t], bv2[t], bv2[t]};
#pragma unroll
        for (int kk = 0; kk < 4; kk++) {
#pragma unroll
            for (int mt = 0; mt < 4; mt++) {
                short8 a = *(const short8*)(ys + (mt * 16 + ln) * YS_STRIDE + kk * 32 + quad * 8);
                acc2[mt][0] = MFMA16(a, b2f[kk][0], acc2[mt][0]);
                acc2[mt][1] = MFMA16(a, b2f[kk][1], acc2[mt][1]);
            }
        }

        // ---- epilogue ----
#pragma unroll
        for (int mt = 0; mt < 4; mt++) {
#pragma unroll
            for (int r = 0; r < 4; r++) {
                const int row = mt * 16 + quad * 4 + r;
                const int nsrc = ridx[row];
#pragma unroll
                for (int t = 0; t < 2; t++) {
                    float s = silu(acc2[mt][t][r]);
                    const int col = ncol0 + t * 16 + ln;
                    mij[(size_t)(e0 + row) * 128 + col] = s;
                    unsafeAtomicAdd(&agg[nsrc * 128 + col], s);
                }
            }
        }
        __syncthreads();  // B4: protect xs/ridx for next tile's staging
    }
}

// ---------------------------------------------------------------------------
// Node kernel: 16-row tiles (625 blocks). a = concat(h, agg/100);
// out = h + silu(a@NW1+nb1)@NW2 + nb2.  V = 10000 = 625*16 exactly.
// ---------------------------------------------------------------------------
__global__ __launch_bounds__(256, 4) void node_kernel(
    const ushort_t* __restrict__ hb, const float* __restrict__ h32,
    const float* __restrict__ agg,
    const ushort_t* __restrict__ w1, const float* __restrict__ nb1,
    const ushort_t* __restrict__ w2, const float* __restrict__ nb2,
    float* __restrict__ out) {
    __shared__ __align__(16) ushort_t xs[16 * XS_STRIDE];  // ys (16*136) overlaid
    ushort_t* ys = xs;

    const int tid = threadIdx.x;
    const int wave = tid >> 6;
    const int lane = tid & 63;
    const int quad = lane >> 4;
    const int ln = lane & 15;
    const int ncol0 = wave * 32;
    const int i0 = blockIdx.x * 16;

    short8 b1f[8][2];
    short8 b2f[4][2];
#pragma unroll
    for (int kk = 0; kk < 8; kk++)
#pragma unroll
        for (int t = 0; t < 2; t++) {
            short8 f;
#pragma unroll
            for (int j = 0; j < 8; j++)
                f[j] = ((const short*)w1)[(kk * 32 + quad * 8 + j) * 128 + ncol0 + t * 16 + ln];
            b1f[kk][t] = f;
        }
#pragma unroll
    for (int kk = 0; kk < 4; kk++)
#pragma unroll
        for (int t = 0; t < 2; t++) {
            short8 f;
#pragma unroll
            for (int j = 0; j < 8; j++)
                f[j] = ((const short*)w2)[(kk * 32 + quad * 8 + j) * 128 + ncol0 + t * 16 + ln];
            b2f[kk][t] = f;
        }
    const float bv1[2] = {nb1[ncol0 + ln], nb1[ncol0 + 16 + ln]};
    const float bv2[2] = {nb2[ncol0 + ln], nb2[ncol0 + 16 + ln]};

    // ---- stage: 16 threads/row; chunks 0..7 = h bf16, 8..15 = agg*0.01 ----
    {
        const int r = tid >> 4, chunk = tid & 15;
        const int node = i0 + r;
        if (chunk < 8) {
            const uint4* src = (const uint4*)(hb + node * 128 + chunk * 16);
            uint4* dst = (uint4*)(xs + r * XS_STRIDE + chunk * 16);
            dst[0] = src[0];
            dst[1] = src[1];
        } else {
            const float4* src = (const float4*)(agg + node * 128 + (chunk - 8) * 16);
            ushort4* dst = (ushort4*)(xs + r * XS_STRIDE + 128 + (chunk - 8) * 16);
#pragma unroll
            for (int u = 0; u < 4; u++) {
                float4 v = src[u];
                ushort4 o;
                o.x = f2b(v.x * 0.01f);
                o.y = f2b(v.y * 0.01f);
                o.z = f2b(v.z * 0.01f);
                o.w = f2b(v.w * 0.01f);
                dst[u] = o;
            }
        }
    }
    __syncthreads();

    // ---- layer 1 (silu) ----
    f32x4 acc[2];
    acc[0] = f32x4{bv1[0], bv1[0], bv1[0], bv1[0]};
    acc[1] = f32x4{bv1[1], bv1[1], bv1[1], bv1[1]};
#pragma unroll
    for (int kk = 0; kk < 8; kk++) {
        short8 a = *(const short8*)(xs + ln * XS_STRIDE + kk * 32 + quad * 8);
        acc[0] = MFMA16(a, b1f[kk][0], acc[0]);
        acc[1] = MFMA16(a, b1f[kk][1], acc[1]);
    }
    __syncthreads();  // xs reads done; overlay ys
#pragma unroll
    for (int t = 0; t < 2; t++)
#pragma unroll
        for (int r = 0; r < 4; r++)
            ys[(quad * 4 + r) * YS_STRIDE + ncol0 + t * 16 + ln] = f2b(silu(acc[t][r]));
    __syncthreads();

    // ---- layer 2 + residual ----
    f32x4 acc2[2];
    acc2[0] = f32x4{bv2[0], bv2[0], bv2[0], bv2[0]};
    acc2[1] = f32x4{bv2[1], bv2[1], bv2[1], bv2[1]};
#pragma unroll
    for (int kk = 0; kk < 4; kk++) {
        short8 a = *(const short8*)(ys + ln * YS_STRIDE + kk * 32 + quad * 8);
        acc2[0] = MFMA16(a, b2f[kk][0], acc2[0]);
        acc2[1] = MFMA16(a, b2f[kk][1], acc2[1]);
    }
#pragma unroll
    for (int r = 0; r < 4; r++) {
        const int node = i0 + quad * 4 + r;
#pragma unroll
        for (int t = 0; t < 2; t++) {
            const int col = ncol0 + t * 16 + ln;
            out[(size_t)node * 128 + col] = h32[(size_t)node * 128 + col] + acc2[t][r];
        }
    }
}

extern "C" void kernel_launch(void* const* d_in, const int* in_sizes, int n_in,
                              void* d_out, int out_size, void* d_ws, size_t ws_size,
                              hipStream_t stream) {
    const float* h = (const float*)d_in[0];
    const int* eidx = (const int*)d_in[1];
    const float* ew1 = (const float*)d_in[2];
    const float* eb1 = (const float*)d_in[3];
    const float* ew2 = (const float*)d_in[4];
    const float* eb2 = (const float*)d_in[5];
    const float* nw1 = (const float*)d_in[6];
    const float* nb1 = (const float*)d_in[7];
    const float* nw2 = (const float*)d_in[8];
    const float* nb2 = (const float*)d_in[9];

    float* out = (float*)d_out;                    // [V,128]
    float* mij = (float*)d_out + (size_t)V * 128;  // [E,128]

    uint8_t* ws = (uint8_t*)d_ws;
    ushort_t* hb = (ushort_t*)(ws);                       // 2,560,000 B
    ushort_t* w1b = (ushort_t*)(ws + 2560000);            // 65,536 B
    ushort_t* w2b = (ushort_t*)(ws + 2560000 + 65536);    // 32,768 B
    ushort_t* nw1b = (ushort_t*)(ws + 2560000 + 98304);   // 65,536 B
    ushort_t* nw2b = (ushort_t*)(ws + 2560000 + 163840);  // 32,768 B
    float* agg = (float*)(ws + 2560000 + 196608);         // 5,120,000 B

    prep_kernel<<<(PREP_TOTAL + 255) / 256, 256, 0, stream>>>(
        h, ew1, ew2, nw1, nw2, hb, w1b, w2b, nw1b, nw2b, agg);
    edge_kernel<<<2048, 256, 0, stream>>>(hb, eidx, w1b, eb1, w2b, eb2, mij, agg);
    node_kernel<<<V / 16, 256, 0, stream>>>(hb, h, agg, nw1b, nb1, nw2b, nb2, out);
}